// Round 3
// baseline (525.611 us; speedup 1.0000x reference)
//
#include <hip/hip_runtime.h>

#define BLOCK   256           // threads per block (4 waves)
#define NBLK    2048          // 8 blocks/CU -> 32 waves/CU (full occupancy)
#define NBINS   256           // global expert-id space
#define NWAVES  (BLOCK / 64)
#define UNROLL  4             // int4 loads per thread per iter (keeps VGPR<=64)
#define NB1     NBLK          // partial slots per bin

// Single fused kernel:
//  - per-wave privatized LDS histogram, inline affine-map detection
//    (round-0 loop verbatim: plain int4, UNROLL=4 -- measured best)
//  - per-block partials written bin-major to ws (no global atomics on data)
//  - last-block-reduces: one atomicAdd on a ws counter per block; the
//    block that observes old == gridDim.x-1 reduces all partials with
//    coalesced int4 reads (L2-resident, ~2-3 us) and writes d_out directly.
// Counter is memset to 0 by a 4-byte hipMemsetAsync (ws is re-poisoned
// every iteration by the harness).
__global__ __launch_bounds__(BLOCK) void hist_fused(const int* __restrict__ ids,
                                                    int N,
                                                    const int* __restrict__ emap,
                                                    int emap_n,
                                                    int* __restrict__ partials,
                                                    unsigned* __restrict__ ctr,
                                                    int* __restrict__ out,
                                                    int n_local) {
    __shared__ int hist[NWAVES * NBINS];
    __shared__ int lmap[NBINS];
    __shared__ int s_lo, s_cnt, s_ok;
    __shared__ unsigned s_old;
    const int tid = threadIdx.x;

    if (tid == 0) { s_lo = 0x7FFFFFFF; s_cnt = 0; s_ok = 1; }
    for (int i = tid; i < NWAVES * NBINS; i += BLOCK) hist[i] = 0;
    __syncthreads();

    // Pass 1: window min + count of valid entries; stash map in LDS.
    for (int g = tid; g < NBINS; g += BLOCK) {
        int m = (g < emap_n) ? emap[g] : -1;
        lmap[g] = m;
        if (m >= 0) { atomicMin(&s_lo, g); atomicAdd(&s_cnt, 1); }
    }
    __syncthreads();
    const int lo = s_lo;
    const unsigned cnt = (unsigned)s_cnt;
    // Pass 2: verify map is exactly the affine window g -> g - lo.
    for (int g = tid; g < NBINS; g += BLOCK) {
        int expect = (g >= lo && (unsigned)(g - lo) < cnt) ? (g - lo) : -1;
        if (lmap[g] != expect) s_ok = 0;   // benign race, all writers store 0
    }
    __syncthreads();
    const int affine = s_ok;

    int* h = &hist[(tid >> 6) * NBINS];

    const int4* __restrict__ ids4 = (const int4*)ids;
    const int n4      = N >> 2;
    const int chunk   = BLOCK * UNROLL;
    const int gstride = (int)gridDim.x * chunk;
    const int n4_full = (n4 / gstride) * gstride;

    if (affine) {
        for (int i = (int)blockIdx.x * chunk + tid; i < n4_full; i += gstride) {
            int4 v[UNROLL];
#pragma unroll
            for (int u = 0; u < UNROLL; ++u) v[u] = ids4[i + u * BLOCK];
#pragma unroll
            for (int u = 0; u < UNROLL; ++u) {
                unsigned a = (unsigned)(v[u].x - lo);
                unsigned b = (unsigned)(v[u].y - lo);
                unsigned c = (unsigned)(v[u].z - lo);
                unsigned d = (unsigned)(v[u].w - lo);
                if (a < cnt) atomicAdd(&h[a], 1);
                if (b < cnt) atomicAdd(&h[b], 1);
                if (c < cnt) atomicAdd(&h[c], 1);
                if (d < cnt) atomicAdd(&h[d], 1);
            }
        }
        for (int i = n4_full + (int)blockIdx.x * BLOCK + tid; i < n4;
             i += (int)gridDim.x * BLOCK) {
            int4 v = ids4[i];
            unsigned a = (unsigned)(v.x - lo), b = (unsigned)(v.y - lo);
            unsigned c = (unsigned)(v.z - lo), d = (unsigned)(v.w - lo);
            if (a < cnt) atomicAdd(&h[a], 1);
            if (b < cnt) atomicAdd(&h[b], 1);
            if (c < cnt) atomicAdd(&h[c], 1);
            if (d < cnt) atomicAdd(&h[d], 1);
        }
        if (blockIdx.x == 0) {
            for (int i = (n4 << 2) + tid; i < N; i += BLOCK) {
                unsigned a = (unsigned)(ids[i] - lo);
                if (a < cnt) atomicAdd(&h[a], 1);
            }
        }
    } else {
        for (int i = (int)blockIdx.x * chunk + tid; i < n4_full; i += gstride) {
            int4 v[UNROLL];
#pragma unroll
            for (int u = 0; u < UNROLL; ++u) v[u] = ids4[i + u * BLOCK];
#pragma unroll
            for (int u = 0; u < UNROLL; ++u) {
                int l0 = ((unsigned)v[u].x < NBINS) ? lmap[v[u].x] : -1;
                int l1 = ((unsigned)v[u].y < NBINS) ? lmap[v[u].y] : -1;
                int l2 = ((unsigned)v[u].z < NBINS) ? lmap[v[u].z] : -1;
                int l3 = ((unsigned)v[u].w < NBINS) ? lmap[v[u].w] : -1;
                if (l0 >= 0) atomicAdd(&h[l0], 1);
                if (l1 >= 0) atomicAdd(&h[l1], 1);
                if (l2 >= 0) atomicAdd(&h[l2], 1);
                if (l3 >= 0) atomicAdd(&h[l3], 1);
            }
        }
        for (int i = n4_full + (int)blockIdx.x * BLOCK + tid; i < n4;
             i += (int)gridDim.x * BLOCK) {
            int4 v = ids4[i];
            int l0 = ((unsigned)v.x < NBINS) ? lmap[v.x] : -1;
            int l1 = ((unsigned)v.y < NBINS) ? lmap[v.y] : -1;
            int l2 = ((unsigned)v.z < NBINS) ? lmap[v.z] : -1;
            int l3 = ((unsigned)v.w < NBINS) ? lmap[v.w] : -1;
            if (l0 >= 0) atomicAdd(&h[l0], 1);
            if (l1 >= 0) atomicAdd(&h[l1], 1);
            if (l2 >= 0) atomicAdd(&h[l2], 1);
            if (l3 >= 0) atomicAdd(&h[l3], 1);
        }
        if (blockIdx.x == 0) {
            for (int i = (n4 << 2) + tid; i < N; i += BLOCK) {
                int v = ids[i];
                int l = ((unsigned)v < NBINS) ? lmap[v] : -1;
                if (l >= 0) atomicAdd(&h[l], 1);
            }
        }
    }
    __syncthreads();

    // Fold wave copies; per-block partials, bin-major so the final reduce
    // reads coalesced. Write traffic 512 KB, merged in L2.
    for (int b = tid; b < n_local; b += BLOCK) {
        int s = 0;
#pragma unroll
        for (int w = 0; w < NWAVES; ++w) s += hist[w * NBINS + b];
        partials[b * NB1 + blockIdx.x] = s;
    }

    // Release: make this block's partials visible, then signal.
    __threadfence();
    __syncthreads();
    if (tid == 0) s_old = atomicAdd(ctr, 1u);
    __syncthreads();
    if (s_old != (unsigned)(gridDim.x - 1)) return;

    // Last block: acquire, then reduce all partials and write out.
    __threadfence();
    const int wave = tid >> 6, lane = tid & 63;
    for (int b = wave; b < n_local; b += NWAVES) {
        const int4* p = (const int4*)&partials[b * NB1];
        int s = 0;
#pragma unroll 2
        for (int j = lane; j < NB1 / 4; j += 64) {   // coalesced 1 KB/step/wave
            int4 v = p[j];
            s += v.x + v.y + v.z + v.w;
        }
#pragma unroll
        for (int off = 32; off > 0; off >>= 1) s += __shfl_down(s, off, 64);
        if (lane == 0) out[b] = s;
    }
}

extern "C" void kernel_launch(void* const* d_in, const int* in_sizes, int n_in,
                              void* d_out, int out_size, void* d_ws, size_t ws_size,
                              hipStream_t stream) {
    const int* topk_ids   = (const int*)d_in[0];
    // d_in[1] = num_local_experts (device scalar) == out_size; use out_size.
    const int* expert_map = (const int*)d_in[2];
    const int N       = in_sizes[0];
    const int emap_n  = in_sizes[2];
    const int n_local = out_size;

    unsigned* ctr = (unsigned*)d_ws;                 // 4 B, zeroed below
    int* partials = (int*)((char*)d_ws + 256);       // n_local * NB1 ints (512 KB)

    hipMemsetAsync(ctr, 0, sizeof(unsigned), stream);
    hist_fused<<<NBLK, BLOCK, 0, stream>>>(topk_ids, N, expert_map, emap_n,
                                           partials, ctr, (int*)d_out, n_local);
}

// Round 4
// 209.940 us; speedup vs baseline: 2.5036x; 2.5036x over previous
//
#include <hip/hip_runtime.h>

#define BLOCK   256           // threads per block (4 waves)
#define NBLK    2048          // 8 blocks/CU -> 32 waves/CU (full occupancy)
#define NBINS   256           // global expert-id space
#define NWAVES  (BLOCK / 64)
#define UNROLL  4             // int4 loads per thread per iter (VGPR<=64, measured best)

// Fused kernel (fence-free): per-wave privatized LDS histogram with inline
// affine-map detection (round-0 loop verbatim -- measured best at 194 us),
// then a direct packed-u64 global-atomic flush into d_out (pre-zeroed by a
// 256 B memset node). Device-scope atomicAdd needs NO threadfence on
// gfx950 (round 3 lesson: per-block __threadfence = L2 writeback per
// block = ~300+ us across 2048 blocks; never use last-block pattern at
// this grid size).
__global__ __launch_bounds__(BLOCK) void hist_fused(const int* __restrict__ ids,
                                                    int N,
                                                    const int* __restrict__ emap,
                                                    int emap_n,
                                                    int* __restrict__ out,
                                                    int n_local) {
    __shared__ int hist[NWAVES * NBINS];
    __shared__ int lmap[NBINS];
    __shared__ int fold[NBINS];
    __shared__ int s_lo, s_cnt, s_ok;
    const int tid = threadIdx.x;

    if (tid == 0) { s_lo = 0x7FFFFFFF; s_cnt = 0; s_ok = 1; }
    for (int i = tid; i < NWAVES * NBINS; i += BLOCK) hist[i] = 0;
    __syncthreads();

    // Pass 1: window min + count of valid entries; stash map in LDS.
    for (int g = tid; g < NBINS; g += BLOCK) {
        int m = (g < emap_n) ? emap[g] : -1;
        lmap[g] = m;
        if (m >= 0) { atomicMin(&s_lo, g); atomicAdd(&s_cnt, 1); }
    }
    __syncthreads();
    const int lo = s_lo;
    const unsigned cnt = (unsigned)s_cnt;
    // Pass 2: verify map is exactly the affine window g -> g - lo.
    for (int g = tid; g < NBINS; g += BLOCK) {
        int expect = (g >= lo && (unsigned)(g - lo) < cnt) ? (g - lo) : -1;
        if (lmap[g] != expect) s_ok = 0;   // benign race, all writers store 0
    }
    __syncthreads();
    const int affine = s_ok;

    int* h = &hist[(tid >> 6) * NBINS];

    const int4* __restrict__ ids4 = (const int4*)ids;
    const int n4      = N >> 2;
    const int chunk   = BLOCK * UNROLL;
    const int gstride = (int)gridDim.x * chunk;
    const int n4_full = (n4 / gstride) * gstride;

    if (affine) {
        for (int i = (int)blockIdx.x * chunk + tid; i < n4_full; i += gstride) {
            int4 v[UNROLL];
#pragma unroll
            for (int u = 0; u < UNROLL; ++u) v[u] = ids4[i + u * BLOCK];
#pragma unroll
            for (int u = 0; u < UNROLL; ++u) {
                unsigned a = (unsigned)(v[u].x - lo);
                unsigned b = (unsigned)(v[u].y - lo);
                unsigned c = (unsigned)(v[u].z - lo);
                unsigned d = (unsigned)(v[u].w - lo);
                if (a < cnt) atomicAdd(&h[a], 1);
                if (b < cnt) atomicAdd(&h[b], 1);
                if (c < cnt) atomicAdd(&h[c], 1);
                if (d < cnt) atomicAdd(&h[d], 1);
            }
        }
        for (int i = n4_full + (int)blockIdx.x * BLOCK + tid; i < n4;
             i += (int)gridDim.x * BLOCK) {
            int4 v = ids4[i];
            unsigned a = (unsigned)(v.x - lo), b = (unsigned)(v.y - lo);
            unsigned c = (unsigned)(v.z - lo), d = (unsigned)(v.w - lo);
            if (a < cnt) atomicAdd(&h[a], 1);
            if (b < cnt) atomicAdd(&h[b], 1);
            if (c < cnt) atomicAdd(&h[c], 1);
            if (d < cnt) atomicAdd(&h[d], 1);
        }
        if (blockIdx.x == 0) {
            for (int i = (n4 << 2) + tid; i < N; i += BLOCK) {
                unsigned a = (unsigned)(ids[i] - lo);
                if (a < cnt) atomicAdd(&h[a], 1);
            }
        }
    } else {
        for (int i = (int)blockIdx.x * chunk + tid; i < n4_full; i += gstride) {
            int4 v[UNROLL];
#pragma unroll
            for (int u = 0; u < UNROLL; ++u) v[u] = ids4[i + u * BLOCK];
#pragma unroll
            for (int u = 0; u < UNROLL; ++u) {
                int l0 = ((unsigned)v[u].x < NBINS) ? lmap[v[u].x] : -1;
                int l1 = ((unsigned)v[u].y < NBINS) ? lmap[v[u].y] : -1;
                int l2 = ((unsigned)v[u].z < NBINS) ? lmap[v[u].z] : -1;
                int l3 = ((unsigned)v[u].w < NBINS) ? lmap[v[u].w] : -1;
                if (l0 >= 0) atomicAdd(&h[l0], 1);
                if (l1 >= 0) atomicAdd(&h[l1], 1);
                if (l2 >= 0) atomicAdd(&h[l2], 1);
                if (l3 >= 0) atomicAdd(&h[l3], 1);
            }
        }
        for (int i = n4_full + (int)blockIdx.x * BLOCK + tid; i < n4;
             i += (int)gridDim.x * BLOCK) {
            int4 v = ids4[i];
            int l0 = ((unsigned)v.x < NBINS) ? lmap[v.x] : -1;
            int l1 = ((unsigned)v.y < NBINS) ? lmap[v.y] : -1;
            int l2 = ((unsigned)v.z < NBINS) ? lmap[v.z] : -1;
            int l3 = ((unsigned)v.w < NBINS) ? lmap[v.w] : -1;
            if (l0 >= 0) atomicAdd(&h[l0], 1);
            if (l1 >= 0) atomicAdd(&h[l1], 1);
            if (l2 >= 0) atomicAdd(&h[l2], 1);
            if (l3 >= 0) atomicAdd(&h[l3], 1);
        }
        if (blockIdx.x == 0) {
            for (int i = (n4 << 2) + tid; i < N; i += BLOCK) {
                int v = ids[i];
                int l = ((unsigned)v < NBINS) ? lmap[v] : -1;
                if (l >= 0) atomicAdd(&h[l], 1);
            }
        }
    }
    __syncthreads();

    // Fold wave copies into fold[] (stride NBINS*4 B between copies:
    // per-thread same-bank walk, 2-way lane aliasing only -> free).
    for (int b = tid; b < n_local; b += BLOCK) {
        int s = 0;
#pragma unroll
        for (int w = 0; w < NWAVES; ++w) s += hist[w * NBINS + b];
        fold[b] = s;
    }
    __syncthreads();

    // Packed flush: 2 bins per u64 atomic (per-bin totals << 2^32, so no
    // carry crosses the 32-bit boundary). Little-endian: u64 at byte 8p
    // covers out[2p] (low) and out[2p+1] (high). 2048 blocks x 32 atomics,
    // pipelined at the coherence point and overlapped with block drain.
    const int npair = n_local >> 1;
    for (int p = tid; p < npair; p += BLOCK) {
        unsigned long long v =
            (unsigned long long)(unsigned)fold[2 * p] |
            ((unsigned long long)(unsigned)fold[2 * p + 1] << 32);
        if (v) atomicAdd((unsigned long long*)out + p, v);
    }
    if ((n_local & 1) && tid == 0) {
        int s = fold[n_local - 1];
        if (s) atomicAdd(&out[n_local - 1], s);
    }
}

extern "C" void kernel_launch(void* const* d_in, const int* in_sizes, int n_in,
                              void* d_out, int out_size, void* d_ws, size_t ws_size,
                              hipStream_t stream) {
    const int* topk_ids   = (const int*)d_in[0];
    // d_in[1] = num_local_experts (device scalar) == out_size; use out_size.
    const int* expert_map = (const int*)d_in[2];
    const int N       = in_sizes[0];
    const int emap_n  = in_sizes[2];
    const int n_local = out_size;

    // Zero the 256 B output (memset node in the captured graph), then one
    // fused kernel accumulates directly into it. No workspace, no fences.
    hipMemsetAsync(d_out, 0, (size_t)n_local * sizeof(int), stream);
    hist_fused<<<NBLK, BLOCK, 0, stream>>>(topk_ids, N, expert_map, emap_n,
                                           (int*)d_out, n_local);
}

// Round 5
// 192.280 us; speedup vs baseline: 2.7336x; 1.0918x over previous
//
#include <hip/hip_runtime.h>

#define BLOCK   256           // threads per block (4 waves)
#define NB1     2048          // histogram blocks (8 per CU -> 32 waves/CU)
#define NBINS   256           // global expert-id space
#define NWAVES  (BLOCK / 64)
#define UNROLL  4             // int4 loads per thread per grid-stride iter

// Measured-best structure (round 0, 194.0 us). Two dispatches:
//   1) hist_part: per-wave privatized LDS histogram, inline affine-map
//      detection, per-block partials stored bin-major to ws (plain stores;
//      NO global atomics -- a 2048-deep atomic flush to d_out measured
//      +16 us of serialized tail; NO threadfence -- per-block device fence
//      measured +330 us of L2 writebacks on gfx950).
//   2) reduce_part: one block per local bin, coalesced int4 sum from L2,
//      direct store (every output element written -> no d_out memset).
// Plain (cacheable) loads: input is partially L3-resident across iterations
// (FETCH_SIZE ~66 MB < 134 MB); nontemporal loads forfeit that (+3.5 us).
__global__ __launch_bounds__(BLOCK) void hist_part(const int* __restrict__ ids,
                                                   int N,
                                                   const int* __restrict__ emap,
                                                   int emap_n,
                                                   int* __restrict__ partials,
                                                   int n_local) {
    __shared__ int hist[NWAVES * NBINS];
    __shared__ int lmap[NBINS];
    __shared__ int s_lo, s_cnt, s_ok;
    const int tid = threadIdx.x;

    if (tid == 0) { s_lo = 0x7FFFFFFF; s_cnt = 0; s_ok = 1; }
    for (int i = tid; i < NWAVES * NBINS; i += BLOCK) hist[i] = 0;
    __syncthreads();

    // Pass 1: window min + count of valid entries; stash map in LDS.
    for (int g = tid; g < NBINS; g += BLOCK) {
        int m = (g < emap_n) ? emap[g] : -1;
        lmap[g] = m;
        if (m >= 0) { atomicMin(&s_lo, g); atomicAdd(&s_cnt, 1); }
    }
    __syncthreads();
    const int lo = s_lo;
    const unsigned cnt = (unsigned)s_cnt;
    // Pass 2: verify map is exactly the affine window g -> g - lo.
    for (int g = tid; g < NBINS; g += BLOCK) {
        int expect = (g >= lo && (unsigned)(g - lo) < cnt) ? (g - lo) : -1;
        if (lmap[g] != expect) s_ok = 0;   // benign race, all writers store 0
    }
    __syncthreads();
    const int affine = s_ok;

    int* h = &hist[(tid >> 6) * NBINS];

    const int4* __restrict__ ids4 = (const int4*)ids;
    const int n4      = N >> 2;
    const int chunk   = BLOCK * UNROLL;
    const int gstride = (int)gridDim.x * chunk;
    const int n4_full = (n4 / gstride) * gstride;

    if (affine) {
        for (int i = (int)blockIdx.x * chunk + tid; i < n4_full; i += gstride) {
            int4 v[UNROLL];
#pragma unroll
            for (int u = 0; u < UNROLL; ++u) v[u] = ids4[i + u * BLOCK];
#pragma unroll
            for (int u = 0; u < UNROLL; ++u) {
                unsigned a = (unsigned)(v[u].x - lo);
                unsigned b = (unsigned)(v[u].y - lo);
                unsigned c = (unsigned)(v[u].z - lo);
                unsigned d = (unsigned)(v[u].w - lo);
                if (a < cnt) atomicAdd(&h[a], 1);
                if (b < cnt) atomicAdd(&h[b], 1);
                if (c < cnt) atomicAdd(&h[c], 1);
                if (d < cnt) atomicAdd(&h[d], 1);
            }
        }
        for (int i = n4_full + (int)blockIdx.x * BLOCK + tid; i < n4;
             i += (int)gridDim.x * BLOCK) {
            int4 v = ids4[i];
            unsigned a = (unsigned)(v.x - lo), b = (unsigned)(v.y - lo);
            unsigned c = (unsigned)(v.z - lo), d = (unsigned)(v.w - lo);
            if (a < cnt) atomicAdd(&h[a], 1);
            if (b < cnt) atomicAdd(&h[b], 1);
            if (c < cnt) atomicAdd(&h[c], 1);
            if (d < cnt) atomicAdd(&h[d], 1);
        }
        if (blockIdx.x == 0) {
            for (int i = (n4 << 2) + tid; i < N; i += BLOCK) {
                unsigned a = (unsigned)(ids[i] - lo);
                if (a < cnt) atomicAdd(&h[a], 1);
            }
        }
    } else {
        for (int i = (int)blockIdx.x * chunk + tid; i < n4_full; i += gstride) {
            int4 v[UNROLL];
#pragma unroll
            for (int u = 0; u < UNROLL; ++u) v[u] = ids4[i + u * BLOCK];
#pragma unroll
            for (int u = 0; u < UNROLL; ++u) {
                int l0 = ((unsigned)v[u].x < NBINS) ? lmap[v[u].x] : -1;
                int l1 = ((unsigned)v[u].y < NBINS) ? lmap[v[u].y] : -1;
                int l2 = ((unsigned)v[u].z < NBINS) ? lmap[v[u].z] : -1;
                int l3 = ((unsigned)v[u].w < NBINS) ? lmap[v[u].w] : -1;
                if (l0 >= 0) atomicAdd(&h[l0], 1);
                if (l1 >= 0) atomicAdd(&h[l1], 1);
                if (l2 >= 0) atomicAdd(&h[l2], 1);
                if (l3 >= 0) atomicAdd(&h[l3], 1);
            }
        }
        for (int i = n4_full + (int)blockIdx.x * BLOCK + tid; i < n4;
             i += (int)gridDim.x * BLOCK) {
            int4 v = ids4[i];
            int l0 = ((unsigned)v.x < NBINS) ? lmap[v.x] : -1;
            int l1 = ((unsigned)v.y < NBINS) ? lmap[v.y] : -1;
            int l2 = ((unsigned)v.z < NBINS) ? lmap[v.z] : -1;
            int l3 = ((unsigned)v.w < NBINS) ? lmap[v.w] : -1;
            if (l0 >= 0) atomicAdd(&h[l0], 1);
            if (l1 >= 0) atomicAdd(&h[l1], 1);
            if (l2 >= 0) atomicAdd(&h[l2], 1);
            if (l3 >= 0) atomicAdd(&h[l3], 1);
        }
        if (blockIdx.x == 0) {
            for (int i = (n4 << 2) + tid; i < N; i += BLOCK) {
                int v = ids[i];
                int l = ((unsigned)v < NBINS) ? lmap[v] : -1;
                if (l >= 0) atomicAdd(&h[l], 1);
            }
        }
    }
    __syncthreads();

    // Fold wave copies; per-block partials, bin-major for coalesced reduce.
    for (int b = tid; b < n_local; b += BLOCK) {
        int s = 0;
#pragma unroll
        for (int w = 0; w < NWAVES; ++w) s += hist[w * NBINS + b];
        partials[b * NB1 + blockIdx.x] = s;
    }
}

// Kernel 2: one block per LOCAL bin; coalesced int4 sum, direct store
// (every output element written each call -> no memset of d_out needed).
__global__ __launch_bounds__(BLOCK) void reduce_part(const int* __restrict__ partials,
                                                     int* __restrict__ out) {
    const int b = blockIdx.x;
    const int tid = threadIdx.x;
    const int4* p = (const int4*)&partials[b * NB1];
    int s = 0;
#pragma unroll
    for (int j = tid; j < NB1 / 4; j += BLOCK) {
        int4 v = p[j];
        s += v.x + v.y + v.z + v.w;
    }
#pragma unroll
    for (int off = 32; off > 0; off >>= 1) s += __shfl_down(s, off, 64);
    __shared__ int wsum[NWAVES];
    if ((tid & 63) == 0) wsum[tid >> 6] = s;
    __syncthreads();
    if (tid == 0) {
        int tot = 0;
#pragma unroll
        for (int w = 0; w < NWAVES; ++w) tot += wsum[w];
        out[b] = tot;
    }
}

extern "C" void kernel_launch(void* const* d_in, const int* in_sizes, int n_in,
                              void* d_out, int out_size, void* d_ws, size_t ws_size,
                              hipStream_t stream) {
    const int* topk_ids   = (const int*)d_in[0];
    // d_in[1] = num_local_experts (device scalar) == out_size; use out_size.
    const int* expert_map = (const int*)d_in[2];
    const int N       = in_sizes[0];
    const int emap_n  = in_sizes[2];
    const int n_local = out_size;

    int* partials = (int*)d_ws;  // n_local * NB1 ints (<= 2 MB)

    hist_part<<<NB1, BLOCK, 0, stream>>>(topk_ids, N, expert_map, emap_n,
                                         partials, n_local);
    reduce_part<<<n_local, BLOCK, 0, stream>>>(partials, (int*)d_out);
}